// Round 11
// baseline (50.752 us; speedup 1.0000x reference)
//
#include <hip/hip_runtime.h>
#include <hip/hip_bf16.h>

#define NQ 16384
#define MM 2048
#define DD 128

typedef __attribute__((ext_vector_type(8))) short bf16x8;
typedef __attribute__((ext_vector_type(4))) float f32x4;
typedef __attribute__((ext_vector_type(16))) float f32x16;

#define MFMA16(a, b, c) __builtin_amdgcn_mfma_f32_16x16x32_bf16((a), (b), (c), 0, 0, 0)
#define MFMA32(a, b, c) __builtin_amdgcn_mfma_f32_32x32x16_bf16((a), (b), (c), 0, 0, 0)
#define MFMA32F8(a, b, c) __builtin_amdgcn_mfma_f32_32x32x16_fp8_fp8((a), (b), (c), 0, 0, 0)

static __device__ __forceinline__ unsigned short f2bf(float x) {
    union { __hip_bfloat16 h; unsigned short u; } cv;
    cv.h = __float2bfloat16(x);
    return cv.u;
}
static __device__ __forceinline__ unsigned pk2(float a, float b) {
    return (unsigned)f2bf(a) | ((unsigned)f2bf(b) << 16);
}
static __device__ __forceinline__ float bfl(unsigned u) {
    union { unsigned v; float f; } c; c.v = u << 16; return c.f;
}
static __device__ __forceinline__ float bfh(unsigned u) {
    union { unsigned v; float f; } c; c.v = u & 0xffff0000u; return c.f;
}
static __device__ __forceinline__ bf16x8 ldbf8(const unsigned short* p) {
    return *reinterpret_cast<const bf16x8*>(p);
}
// pack 4 floats -> 4 fp8 e4m3 bytes (OCP on gfx950)
static __device__ __forceinline__ unsigned pk4f8(float a, float b, float c, float d) {
    int v = __builtin_amdgcn_cvt_pk_fp8_f32(a, b, 0, false);
    v = __builtin_amdgcn_cvt_pk_fp8_f32(c, d, v, true);
    return (unsigned)v;
}
static __device__ __forceinline__ unsigned char f8b(float x) {
    return (unsigned char)(__builtin_amdgcn_cvt_pk_fp8_f32(x, x, 0, false) & 0xff);
}

union AW { unsigned u[4]; bf16x8 v; };

// ---------------------------------------------------------------------------
// K01: prep, fp8 fragment packing for the m-streams (unchanged from r10).
// ---------------------------------------------------------------------------
__global__ __launch_bounds__(256) void k01_prep(const float* __restrict__ miw,
                                                const float* __restrict__ mw,
                                                const float* __restrict__ wt,
                                                const float* __restrict__ wt2,
                                                unsigned char* __restrict__ minnA8,
                                                unsigned char* __restrict__ mwB8,
                                                unsigned short* __restrict__ wtb,
                                                unsigned short* __restrict__ wt2f) {
    int b = blockIdx.x;
    int t = threadIdx.x;
    if (b >= 64) {
        int i = (b - 64) * 1024 + t * 4;   // 48 blocks cover 49152 elems
        if (i < DD * DD) {
            float4 x = *reinterpret_cast<const float4*>(wt + i);
            *reinterpret_cast<uint2*>(wtb + i) = make_uint2(pk2(x.x, x.y), pk2(x.z, x.w));
        } else {
            int j = i - DD * DD;           // index into wt2 [128][256]
            float4 x = *reinterpret_cast<const float4*>(wt2 + j);
            int row = j >> 8, col = j & 255;
            unsigned short* dst = wt2f +
                (((((col >> 4) * 4 + (row >> 5)) * 64) + ((col >> 3) & 1) * 32 + (row & 31)) << 3) +
                (col & 7);
            dst[0] = f2bf(x.x); dst[1] = f2bf(x.y); dst[2] = f2bf(x.z); dst[3] = f2bf(x.w);
        }
        return;
    }
    int r = t >> 3;              // tile row 0..31
    int e = t & 7;               // 16-col group 0..7
    int m = b * 32 + r;

    float v[16];
    float ss = 0.f;
#pragma unroll
    for (int k = 0; k < 4; ++k) {
        float4 x = reinterpret_cast<const float4*>(miw + m * DD + e * 16)[k];
        v[4 * k] = x.x; v[4 * k + 1] = x.y; v[4 * k + 2] = x.z; v[4 * k + 3] = x.w;
        ss += x.x * x.x + x.y * x.y + x.z * x.z + x.w * x.w;
    }
    ss += __shfl_xor(ss, 1); ss += __shfl_xor(ss, 2); ss += __shfl_xor(ss, 4);
    float sc = 1.0f / fmaxf(sqrtf(ss), 1e-8f);

    {
        unsigned lo0 = pk4f8(v[0] * sc, v[1] * sc, v[2] * sc, v[3] * sc);
        unsigned lo1 = pk4f8(v[4] * sc, v[5] * sc, v[6] * sc, v[7] * sc);
        unsigned hi0 = pk4f8(v[8] * sc, v[9] * sc, v[10] * sc, v[11] * sc);
        unsigned hi1 = pk4f8(v[12] * sc, v[13] * sc, v[14] * sc, v[15] * sc);
        *reinterpret_cast<uint2*>(minnA8 + ((((b * 8 + e) * 64) + r) << 3)) = make_uint2(lo0, lo1);
        *reinterpret_cast<uint2*>(minnA8 + ((((b * 8 + e) * 64) + 32 + r) << 3)) = make_uint2(hi0, hi1);
    }

    float w[16];
#pragma unroll
    for (int k = 0; k < 4; ++k) {
        float4 x = reinterpret_cast<const float4*>(mw + m * DD + e * 16)[k];
        w[4 * k] = x.x; w[4 * k + 1] = x.y; w[4 * k + 2] = x.z; w[4 * k + 3] = x.w;
    }
    int kc = r >> 4, hh = (r >> 3) & 1, jj = r & 7;
    unsigned char* base = mwB8 +
        ((((b * 8 + kc * 4 + (e >> 1)) * 64) + hh * 32 + (e & 1) * 16) << 3) + jj;
#pragma unroll
    for (int u = 0; u < 16; ++u) base[u << 3] = f8b(w[u]);
}

// ---------------------------------------------------------------------------
// K3: fused transform + attention + gating, fp8 streams, REAL register
// double-buffer.  Grid 512 x 256thr (4 waves = m-quarters), 32 q/block.
// __launch_bounds__(256,1): 512-VGPR cap so the 2-tile fragment buffers
// (~190 VGPR total state) actually live in registers -> prefetch of tile
// it+1 overlaps the full compute of tile it.  Linear tile walk (induction-
// variable addressing).  Raw query tile stashed in LDS for the epilogue.
// ---------------------------------------------------------------------------
__global__ __launch_bounds__(256, 1) void k3_fused(const float* __restrict__ query,
                                                   const unsigned short* __restrict__ wtb,
                                                   const float* __restrict__ bt,
                                                   const unsigned char* __restrict__ minnA8,
                                                   const unsigned char* __restrict__ mwB8,
                                                   const unsigned short* __restrict__ wt2f,
                                                   const float* __restrict__ bt2,
                                                   float* __restrict__ me_out,
                                                   float* __restrict__ out) {
    // [0,26112):     3 reduction slots of 8704 B
    // [26112,34816): tqm 32 rows x 136 shorts (tq_n bf16; later me tile)
    // [34816,51712): qf32 raw query tile, 32 rows x 132 floats (padded)
    __shared__ __align__(16) char pool[51712];
    unsigned short* tqm = reinterpret_cast<unsigned short*>(pool + 26112);
    float* qf32 = reinterpret_cast<float*>(pool + 34816);

    const int lane = threadIdx.x & 63;
    const int wid = threadIdx.x >> 6;   // m-quarter 0..3
    const int ml = lane & 31;
    const int hi = lane >> 5;
    const int n0 = blockIdx.x * 32;
    const float L2E = 1.44269504088896340736f;

    // ---- Phase 0: transform 32 q (waves 0,1; 16 q each); also stash raw q
    if (wid < 2) {
        const int nl = lane & 15;
        const int g = lane >> 4;
        const int qb = n0 + 16 * wid;
        AW aq[4];
#pragma unroll
        for (int c = 0; c < 4; ++c) {
            const float* p = query + (qb + nl) * DD + 32 * c + 8 * g;
            float4 x0 = reinterpret_cast<const float4*>(p)[0];
            float4 x1 = reinterpret_cast<const float4*>(p)[1];
            aq[c].u[0] = pk2(x0.x, x0.y); aq[c].u[1] = pk2(x0.z, x0.w);
            aq[c].u[2] = pk2(x1.x, x1.y); aq[c].u[3] = pk2(x1.z, x1.w);
            float* qd = qf32 + (16 * wid + nl) * 132 + 32 * c + 8 * g;
            *reinterpret_cast<float4*>(qd) = x0;
            *reinterpret_cast<float4*>(qd + 4) = x1;
        }
        f32x4 acc[8];
#pragma unroll
        for (int t = 0; t < 8; ++t) acc[t] = (f32x4){0.f, 0.f, 0.f, 0.f};
#pragma unroll
        for (int t = 0; t < 8; ++t)
#pragma unroll
            for (int c = 0; c < 4; ++c) {
                bf16x8 bv = ldbf8(wtb + (16 * t + nl) * DD + 32 * c + 8 * g);
                acc[t] = MFMA16(aq[c].v, bv, acc[t]);
            }
        float ss[4] = {0.f, 0.f, 0.f, 0.f};
#pragma unroll
        for (int t = 0; t < 8; ++t) {
            float bias = bt[16 * t + nl];
#pragma unroll
            for (int r = 0; r < 4; ++r) {
                float vv = acc[t][r] + bias;
                acc[t][r] = vv;
                ss[r] += vv * vv;
            }
        }
#pragma unroll
        for (int r = 0; r < 4; ++r) {
            ss[r] += __shfl_xor(ss[r], 1);
            ss[r] += __shfl_xor(ss[r], 2);
            ss[r] += __shfl_xor(ss[r], 4);
            ss[r] += __shfl_xor(ss[r], 8);
        }
        float scl[4];
#pragma unroll
        for (int r = 0; r < 4; ++r) scl[r] = L2E / fmaxf(sqrtf(ss[r]), 1e-8f);
#pragma unroll
        for (int t = 0; t < 8; ++t)
#pragma unroll
            for (int r = 0; r < 4; ++r)
                tqm[(16 * wid + 4 * g + r) * 136 + 16 * t + nl] = f2bf(acc[t][r] * scl[r]);
    }
    __syncthreads();  // tqm + qf32 visible to all waves

    // Qn fp8 B-fragments built in registers from the bf16 tile
    long qn8[8];
#pragma unroll
    for (int c = 0; c < 8; ++c) {
        bf16x8 qv = ldbf8(&tqm[ml * 136 + 16 * c + 8 * hi]);
        const unsigned* qu = reinterpret_cast<const unsigned*>(&qv);
        unsigned lo = pk4f8(bfl(qu[0]), bfh(qu[0]), bfl(qu[1]), bfh(qu[1]));
        unsigned hh = pk4f8(bfl(qu[2]), bfh(qu[2]), bfl(qu[3]), bfh(qu[3]));
        qn8[c] = (long)(((unsigned long long)hh << 32) | lo);
    }

    const f32x16 zero16 = {0.f,0.f,0.f,0.f,0.f,0.f,0.f,0.f,0.f,0.f,0.f,0.f,0.f,0.f,0.f,0.f};
    f32x16 o[4];
#pragma unroll
    for (int t = 0; t < 4; ++t) o[t] = zero16;
    float den = 0.0f;

    // this quarter's fragment streams: frag (it,c) at + it*4096 + c*512 + lane*8
    const unsigned char* pa = minnA8 + (size_t)wid * 65536 + lane * 8;
    const unsigned char* pb = mwB8 + (size_t)wid * 65536 + lane * 8;

    long aA8[2][8], bw8[2][8];
#pragma unroll
    for (int c = 0; c < 8; ++c) {   // prologue: tile 0
        aA8[0][c] = *reinterpret_cast<const long*>(pa + c * 512);
        bw8[0][c] = *reinterpret_cast<const long*>(pb + c * 512);
    }

#pragma unroll 2
    for (int it = 0; it < 16; ++it) {
        const int cur = it & 1;
        // prefetch next tile's fragments (dense 512B loads, independent regs)
        if (it < 15) {
#pragma unroll
            for (int c = 0; c < 8; ++c)
                aA8[cur ^ 1][c] = *reinterpret_cast<const long*>(pa + (it + 1) * 4096 + c * 512);
#pragma unroll
            for (int q = 0; q < 8; ++q)
                bw8[cur ^ 1][q] = *reinterpret_cast<const long*>(pb + (it + 1) * 4096 + q * 512);
        }

        // QK^T: D[m][n], two 4-deep accumulate chains over d (K=16 each)
        f32x16 sA = zero16, sB = zero16;
#pragma unroll
        for (int c = 0; c < 4; ++c) sA = MFMA32F8(aA8[cur][c], qn8[c], sA);
#pragma unroll
        for (int c = 4; c < 8; ++c) sB = MFMA32F8(aA8[cur][c], qn8[c], sB);

        float p[16];
#pragma unroll
        for (int r = 0; r < 16; ++r)
            p[r] = __builtin_amdgcn_exp2f(sA[r] + sB[r]);
        {
            float e0 = (p[0] + p[1]) + (p[2] + p[3]);
            float e1 = (p[4] + p[5]) + (p[6] + p[7]);
            float e2 = (p[8] + p[9]) + (p[10] + p[11]);
            float e3 = (p[12] + p[13]) + (p[14] + p[15]);
            den += (e0 + e1) + (e2 + e3);
        }
        // pack P to fp8; one permlane pair builds both PV A-operands
        unsigned u0 = pk4f8(p[0], p[1], p[2], p[3]);
        unsigned u1 = pk4f8(p[4], p[5], p[6], p[7]);
        unsigned u2 = pk4f8(p[8], p[9], p[10], p[11]);
        unsigned u3 = pk4f8(p[12], p[13], p[14], p[15]);
        auto s01 = __builtin_amdgcn_permlane32_swap(u0, u1, false, false);
        auto s23 = __builtin_amdgcn_permlane32_swap(u2, u3, false, false);
        long aP0 = (long)(((unsigned long long)(unsigned)s01[1] << 32) | (unsigned)s01[0]);
        long aP1 = (long)(((unsigned long long)(unsigned)s23[1] << 32) | (unsigned)s23[0]);
        // PV: aP0 with bw8[0..3] (kc=0), aP1 with bw8[4..7] (kc=1)
#pragma unroll
        for (int dt = 0; dt < 4; ++dt) {
            o[dt] = MFMA32F8(aP0, bw8[cur][dt], o[dt]);
            o[dt] = MFMA32F8(aP1, bw8[cur][4 + dt], o[dt]);
        }
    }

    // ---- cross-quarter reduction (bf16 partials + f32 den) ----
    __syncthreads();
    if (wid >= 1) {
        char* dst = pool + (wid - 1) * 8704 + lane * 136;
#pragma unroll
        for (int t = 0; t < 4; ++t) {
            unsigned u[8];
#pragma unroll
            for (int k = 0; k < 8; ++k) u[k] = pk2(o[t][2 * k], o[t][2 * k + 1]);
            *reinterpret_cast<uint4*>(dst + t * 32) = make_uint4(u[0], u[1], u[2], u[3]);
            *reinterpret_cast<uint4*>(dst + t * 32 + 16) = make_uint4(u[4], u[5], u[6], u[7]);
        }
        *reinterpret_cast<float*>(dst + 128) = den;
    }
    __syncthreads();
    if (wid == 0) {
        for (int s = 0; s < 3; ++s) {
            const char* src = pool + s * 8704 + lane * 136;
#pragma unroll
            for (int t = 0; t < 4; ++t) {
                uint4 ua = *reinterpret_cast<const uint4*>(src + t * 32);
                uint4 ub = *reinterpret_cast<const uint4*>(src + t * 32 + 16);
                unsigned u[8] = {ua.x, ua.y, ua.z, ua.w, ub.x, ub.y, ub.z, ub.w};
#pragma unroll
                for (int k = 0; k < 8; ++k) {
                    o[t][2 * k] += bfl(u[k]);
                    o[t][2 * k + 1] += bfh(u[k]);
                }
            }
            den += *reinterpret_cast<const float*>(src + 128);
        }
        den += __shfl_xor(den, 32);
        float invd = 1.0f / den;
        float inv[16];
#pragma unroll
        for (int r = 0; r < 16; ++r)
            inv[r] = __shfl(invd, (r & 3) + 8 * (r >> 2) + 4 * hi);
#pragma unroll
        for (int t = 0; t < 4; ++t)
#pragma unroll
            for (int r = 0; r < 16; ++r) {
                int row = (r & 3) + 8 * (r >> 2) + 4 * hi;
                float me = o[t][r] * inv[r];
                me_out[(n0 + row) * DD + 32 * t + ml] = me;
                tqm[row * 136 + 32 * t + ml] = f2bf(me);  // me tile for gating
            }
    }
    __syncthreads();

    // ---- fused gating: G = tanh(cat(me,q) @ W_t2^T + b_t2); blend ----
    {
        const int dt = wid;  // d-tile 32*dt .. 32*dt+31
        f32x16 g = zero16;
#pragma unroll
        for (int c = 0; c < 8; ++c) {  // k < 128: me from LDS tile
            bf16x8 av = ldbf8(&tqm[ml * 136 + 16 * c + 8 * hi]);
            bf16x8 bv = ldbf8(wt2f + ((c * 4 + dt) * 64 + lane) * 8);
            g = MFMA32(av, bv, g);
        }
#pragma unroll
        for (int c = 8; c < 16; ++c) {  // k >= 128: query from LDS (f32)
            const float* p = qf32 + ml * 132 + 16 * (c - 8) + 8 * hi;
            float4 x0 = *reinterpret_cast<const float4*>(p);
            float4 x1 = *reinterpret_cast<const float4*>(p + 4);
            AW av;
            av.u[0] = pk2(x0.x, x0.y); av.u[1] = pk2(x0.z, x0.w);
            av.u[2] = pk2(x1.x, x1.y); av.u[3] = pk2(x1.z, x1.w);
            bf16x8 bv = ldbf8(wt2f + ((c * 4 + dt) * 64 + lane) * 8);
            g = MFMA32(av.v, bv, g);
        }
        const float TWO_L2E = 2.88539008177792681472f;  // 2*log2(e)
        const int d = 32 * dt + ml;
        const float bias = bt2[d];
#pragma unroll
        for (int r = 0; r < 16; ++r) {
            int row = (r & 3) + 8 * (r >> 2) + 4 * hi;
            float x = g[r] + bias;
            float gt = 1.0f - 2.0f / (__builtin_amdgcn_exp2f(x * TWO_L2E) + 1.0f);
            float qv = qf32[row * 132 + d];
            float mv = bfl(tqm[row * 136 + d]);
            out[(n0 + row) * DD + d] = qv + gt * (mv - qv);
        }
    }
}

// ---------------------------------------------------------------------------
extern "C" void kernel_launch(void* const* d_in, const int* in_sizes, int n_in,
                              void* d_out, int out_size, void* d_ws, size_t ws_size,
                              hipStream_t stream) {
    const float* query = (const float*)d_in[0];   // [N,128]
    const float* wt    = (const float*)d_in[1];   // [128,128]
    const float* bt    = (const float*)d_in[2];   // [128]
    const float* miw   = (const float*)d_in[3];   // [M,128]
    const float* mw    = (const float*)d_in[4];   // [M,128]
    const float* wt2   = (const float*)d_in[5];   // [128,256]
    const float* bt2   = (const float*)d_in[6];   // [128]

    float* out    = (float*)d_out;                // output 0: [N,128]
    float* me_out = out + (size_t)NQ * DD;        // output 1: mem_emb [N,128]

    // workspace: fp8 m-streams + bf16 weights, ~0.6 MB
    unsigned char* minnA8 = (unsigned char*)d_ws;               // [M/32][8][64][8] fp8
    unsigned char* mwB8   = minnA8 + (size_t)MM * DD;           // [M/32][8][64][8] fp8
    unsigned short* wtb   = (unsigned short*)(mwB8 + (size_t)MM * DD);  // [128][128] bf16
    unsigned short* wt2f  = wtb + (size_t)DD * DD;              // [16][4][64][8] bf16

    k01_prep<<<112, 256, 0, stream>>>(miw, mw, wt, wt2, minnA8, mwB8, wtb, wt2f);
    k3_fused<<<NQ / 32, 256, 0, stream>>>(query, wtb, bt, minnA8, mwB8, wt2f, bt2,
                                          me_out, out);
}

// Round 12
// 41.740 us; speedup vs baseline: 1.2159x; 1.2159x over previous
//
#include <hip/hip_runtime.h>
#include <hip/hip_bf16.h>

#define NQ 16384
#define MM 2048
#define DD 128

typedef __attribute__((ext_vector_type(8))) short bf16x8;
typedef __attribute__((ext_vector_type(4))) float f32x4;
typedef __attribute__((ext_vector_type(16))) float f32x16;

#define MFMA16(a, b, c) __builtin_amdgcn_mfma_f32_16x16x32_bf16((a), (b), (c), 0, 0, 0)
#define MFMA32(a, b, c) __builtin_amdgcn_mfma_f32_32x32x16_bf16((a), (b), (c), 0, 0, 0)
#define MFMA32F8(a, b, c) __builtin_amdgcn_mfma_f32_32x32x16_fp8_fp8((a), (b), (c), 0, 0, 0)

static __device__ __forceinline__ unsigned short f2bf(float x) {
    union { __hip_bfloat16 h; unsigned short u; } cv;
    cv.h = __float2bfloat16(x);
    return cv.u;
}
static __device__ __forceinline__ unsigned pk2(float a, float b) {
    return (unsigned)f2bf(a) | ((unsigned)f2bf(b) << 16);
}
static __device__ __forceinline__ float bfl(unsigned u) {
    union { unsigned v; float f; } c; c.v = u << 16; return c.f;
}
static __device__ __forceinline__ float bfh(unsigned u) {
    union { unsigned v; float f; } c; c.v = u & 0xffff0000u; return c.f;
}
static __device__ __forceinline__ bf16x8 ldbf8(const unsigned short* p) {
    return *reinterpret_cast<const bf16x8*>(p);
}
// pack 4 floats -> 4 fp8 e4m3 bytes (OCP on gfx950)
static __device__ __forceinline__ unsigned pk4f8(float a, float b, float c, float d) {
    int v = __builtin_amdgcn_cvt_pk_fp8_f32(a, b, 0, false);
    v = __builtin_amdgcn_cvt_pk_fp8_f32(c, d, v, true);
    return (unsigned)v;
}
static __device__ __forceinline__ unsigned char f8b(float x) {
    return (unsigned char)(__builtin_amdgcn_cvt_pk_fp8_f32(x, x, 0, false) & 0xff);
}

union AW { unsigned u[4]; bf16x8 v; };

// ---------------------------------------------------------------------------
// K01: prep, fp8 fragment packing for the m-streams (unchanged from r10/r11).
// minnA8[(tile32*8+c)*64+lane][8]; mwB8[(tile32*8+kc*4+dt)*64+lane][8].
// ---------------------------------------------------------------------------
__global__ __launch_bounds__(256) void k01_prep(const float* __restrict__ miw,
                                                const float* __restrict__ mw,
                                                const float* __restrict__ wt,
                                                const float* __restrict__ wt2,
                                                unsigned char* __restrict__ minnA8,
                                                unsigned char* __restrict__ mwB8,
                                                unsigned short* __restrict__ wtb,
                                                unsigned short* __restrict__ wt2f) {
    int b = blockIdx.x;
    int t = threadIdx.x;
    if (b >= 64) {
        int i = (b - 64) * 1024 + t * 4;   // 48 blocks cover 49152 elems
        if (i < DD * DD) {
            float4 x = *reinterpret_cast<const float4*>(wt + i);
            *reinterpret_cast<uint2*>(wtb + i) = make_uint2(pk2(x.x, x.y), pk2(x.z, x.w));
        } else {
            int j = i - DD * DD;           // index into wt2 [128][256]
            float4 x = *reinterpret_cast<const float4*>(wt2 + j);
            int row = j >> 8, col = j & 255;
            unsigned short* dst = wt2f +
                (((((col >> 4) * 4 + (row >> 5)) * 64) + ((col >> 3) & 1) * 32 + (row & 31)) << 3) +
                (col & 7);
            dst[0] = f2bf(x.x); dst[1] = f2bf(x.y); dst[2] = f2bf(x.z); dst[3] = f2bf(x.w);
        }
        return;
    }
    int r = t >> 3;              // tile row 0..31
    int e = t & 7;               // 16-col group 0..7
    int m = b * 32 + r;

    float v[16];
    float ss = 0.f;
#pragma unroll
    for (int k = 0; k < 4; ++k) {
        float4 x = reinterpret_cast<const float4*>(miw + m * DD + e * 16)[k];
        v[4 * k] = x.x; v[4 * k + 1] = x.y; v[4 * k + 2] = x.z; v[4 * k + 3] = x.w;
        ss += x.x * x.x + x.y * x.y + x.z * x.z + x.w * x.w;
    }
    ss += __shfl_xor(ss, 1); ss += __shfl_xor(ss, 2); ss += __shfl_xor(ss, 4);
    float sc = 1.0f / fmaxf(sqrtf(ss), 1e-8f);

    {
        unsigned lo0 = pk4f8(v[0] * sc, v[1] * sc, v[2] * sc, v[3] * sc);
        unsigned lo1 = pk4f8(v[4] * sc, v[5] * sc, v[6] * sc, v[7] * sc);
        unsigned hi0 = pk4f8(v[8] * sc, v[9] * sc, v[10] * sc, v[11] * sc);
        unsigned hi1 = pk4f8(v[12] * sc, v[13] * sc, v[14] * sc, v[15] * sc);
        *reinterpret_cast<uint2*>(minnA8 + ((((b * 8 + e) * 64) + r) << 3)) = make_uint2(lo0, lo1);
        *reinterpret_cast<uint2*>(minnA8 + ((((b * 8 + e) * 64) + 32 + r) << 3)) = make_uint2(hi0, hi1);
    }

    float w[16];
#pragma unroll
    for (int k = 0; k < 4; ++k) {
        float4 x = reinterpret_cast<const float4*>(mw + m * DD + e * 16)[k];
        w[4 * k] = x.x; w[4 * k + 1] = x.y; w[4 * k + 2] = x.z; w[4 * k + 3] = x.w;
    }
    int kc = r >> 4, hh = (r >> 3) & 1, jj = r & 7;
    unsigned char* base = mwB8 +
        ((((b * 8 + kc * 4 + (e >> 1)) * 64) + hh * 32 + (e & 1) * 16) << 3) + jj;
#pragma unroll
    for (int u = 0; u < 16; ++u) base[u << 3] = f8b(w[u]);
}

// ---------------------------------------------------------------------------
// K3: fused transform + attention + gating.  GEMM-style LDS staging:
// Grid 256 x 512thr (1 block/CU; 8 waves = 2 q-halves x 4 m-subs).
// Per 128-m tile the block stages 32 KB of fp8 fragments (minn 16K + mw 16K)
// into LDS ONCE via global_load_lds (4x16B per wave), double-buffered with
// counted vmcnt(4) + 2 barriers/iter.  All 8 waves consume via ds_read.
// Per-CU global pull: 512 KB total (vs 1 MB r11).  Epilogue: per-q-half
// cross-sub reduction + fused gating (query tile cached in LDS as f32).
// ---------------------------------------------------------------------------
__global__ __launch_bounds__(512, 2) void k3_fused(const float* __restrict__ query,
                                                   const unsigned short* __restrict__ wtb,
                                                   const float* __restrict__ bt,
                                                   const unsigned char* __restrict__ minnA8,
                                                   const unsigned char* __restrict__ mwB8,
                                                   const unsigned short* __restrict__ wt2f,
                                                   const float* __restrict__ bt2,
                                                   float* __restrict__ me_out,
                                                   float* __restrict__ out) {
    // [0,65536):       staging double buffer (buf0 @0, buf1 @32768);
    //                  each buf: [0,16K) minn image, [16K,32K) mw image
    //                  (aliased post-loop: 6 reduction slots of 8704 B)
    // [65536,82944):   tqm 64 rows x 136 shorts (tq_n bf16; later me tile)
    // [82944,116736):  qf32 raw query tile, 64 rows x 132 floats
    __shared__ __align__(16) char pool[116736];
    unsigned short* tqm = reinterpret_cast<unsigned short*>(pool + 65536);
    float* qf32 = reinterpret_cast<float*>(pool + 82944);

    const int lane = threadIdx.x & 63;
    const int wid = threadIdx.x >> 6;   // 0..7
    const int qh = wid >> 2;            // q-half (32 q)
    const int ms = wid & 3;             // m-sub (32 m of each 128-m tile)
    const int ml = lane & 31;
    const int hi = lane >> 5;
    const int n0 = blockIdx.x * 64;
    const float L2E = 1.44269504088896340736f;

    // stage one 128-m tile (32 KB: minn 16K + mw 16K) into buf; wave w does
    // 4 x 1KB segments.  Images are exact copies -> fragment offsets preserved.
    auto stage = [&](int it, char* buf) {
        const unsigned char* garr = (wid < 4) ? minnA8 : mwB8;
        const int reg = (wid & 3) * 4096;
        const int ldsb = ((wid < 4) ? 0 : 16384) + reg;
#pragma unroll
        for (int k = 0; k < 4; ++k) {
            const unsigned char* src = garr + (size_t)it * 16384 + reg + k * 1024 + lane * 16;
            __builtin_amdgcn_global_load_lds(
                (const __attribute__((address_space(1))) unsigned int*)src,
                (__attribute__((address_space(3))) unsigned int*)(buf + ldsb + k * 1024),
                16, 0, 0);
        }
    };

    // prologue: start DMA of tile 0 (lands under phase-0 compute)
    stage(0, pool);

    // ---- Phase 0: transform 64 q (waves 0..3, 16 q each); stash raw q f32
    if (wid < 4) {
        const int nl = lane & 15;
        const int g = lane >> 4;
        const int qb = n0 + 16 * wid;
        AW aq[4];
#pragma unroll
        for (int c = 0; c < 4; ++c) {
            const float* p = query + (qb + nl) * DD + 32 * c + 8 * g;
            float4 x0 = reinterpret_cast<const float4*>(p)[0];
            float4 x1 = reinterpret_cast<const float4*>(p)[1];
            aq[c].u[0] = pk2(x0.x, x0.y); aq[c].u[1] = pk2(x0.z, x0.w);
            aq[c].u[2] = pk2(x1.x, x1.y); aq[c].u[3] = pk2(x1.z, x1.w);
            float* qd = qf32 + (16 * wid + nl) * 132 + 32 * c + 8 * g;
            *reinterpret_cast<float4*>(qd) = x0;
            *reinterpret_cast<float4*>(qd + 4) = x1;
        }
        f32x4 acc[8];
#pragma unroll
        for (int t = 0; t < 8; ++t) acc[t] = (f32x4){0.f, 0.f, 0.f, 0.f};
#pragma unroll
        for (int t = 0; t < 8; ++t)
#pragma unroll
            for (int c = 0; c < 4; ++c) {
                bf16x8 bv = ldbf8(wtb + (16 * t + nl) * DD + 32 * c + 8 * g);
                acc[t] = MFMA16(aq[c].v, bv, acc[t]);
            }
        float ss[4] = {0.f, 0.f, 0.f, 0.f};
#pragma unroll
        for (int t = 0; t < 8; ++t) {
            float bias = bt[16 * t + nl];
#pragma unroll
            for (int r = 0; r < 4; ++r) {
                float vv = acc[t][r] + bias;
                acc[t][r] = vv;
                ss[r] += vv * vv;
            }
        }
#pragma unroll
        for (int r = 0; r < 4; ++r) {
            ss[r] += __shfl_xor(ss[r], 1);
            ss[r] += __shfl_xor(ss[r], 2);
            ss[r] += __shfl_xor(ss[r], 4);
            ss[r] += __shfl_xor(ss[r], 8);
        }
        float scl[4];
#pragma unroll
        for (int r = 0; r < 4; ++r) scl[r] = L2E / fmaxf(sqrtf(ss[r]), 1e-8f);
#pragma unroll
        for (int t = 0; t < 8; ++t)
#pragma unroll
            for (int r = 0; r < 4; ++r)
                tqm[(16 * wid + 4 * g + r) * 136 + 16 * t + nl] = f2bf(acc[t][r] * scl[r]);
    }
    __syncthreads();  // tqm/qf32 visible; tile-0 DMA drained (vmcnt 0 at barrier)

    // Qn fp8 B-fragments for this wave's q-half, built from the bf16 tile
    long qn8[8];
#pragma unroll
    for (int c = 0; c < 8; ++c) {
        bf16x8 qv = ldbf8(&tqm[(32 * qh + ml) * 136 + 16 * c + 8 * hi]);
        const unsigned* qu = reinterpret_cast<const unsigned*>(&qv);
        unsigned lo = pk4f8(bfl(qu[0]), bfh(qu[0]), bfl(qu[1]), bfh(qu[1]));
        unsigned hh = pk4f8(bfl(qu[2]), bfh(qu[2]), bfl(qu[3]), bfh(qu[3]));
        qn8[c] = (long)(((unsigned long long)hh << 32) | lo);
    }

    const f32x16 zero16 = {0.f,0.f,0.f,0.f,0.f,0.f,0.f,0.f,0.f,0.f,0.f,0.f,0.f,0.f,0.f,0.f};
    f32x16 o[4];
#pragma unroll
    for (int t = 0; t < 4; ++t) o[t] = zero16;
    float den = 0.0f;

    for (int it = 0; it < 16; ++it) {
        char* buf = pool + ((it & 1) ? 32768 : 0);
        char* nbuf = pool + ((it & 1) ? 0 : 32768);
        if (it < 15) {
            stage(it + 1, nbuf);
            asm volatile("s_waitcnt vmcnt(4)" ::: "memory");  // tile `it` landed
        } else {
            asm volatile("s_waitcnt vmcnt(0)" ::: "memory");
        }
        __builtin_amdgcn_sched_barrier(0);
        __builtin_amdgcn_s_barrier();      // all waves' segments of tile `it` in
        __builtin_amdgcn_sched_barrier(0);

        // fragments for this wave's m-sub from the LDS images (dense 512B/read-set)
        const char* amin = buf + ms * 4096 + lane * 8;
        const char* bmw = buf + 16384 + ms * 4096 + lane * 8;
        long aA8[8], bw8[8];
#pragma unroll
        for (int c = 0; c < 8; ++c) {
            aA8[c] = *reinterpret_cast<const long*>(amin + c * 512);
            bw8[c] = *reinterpret_cast<const long*>(bmw + c * 512);
        }

        // QK^T: D[m][n], two 4-deep accumulate chains over d (K=16 each)
        f32x16 sA = zero16, sB = zero16;
#pragma unroll
        for (int c = 0; c < 4; ++c) sA = MFMA32F8(aA8[c], qn8[c], sA);
#pragma unroll
        for (int c = 4; c < 8; ++c) sB = MFMA32F8(aA8[c], qn8[c], sB);

        float p[16];
#pragma unroll
        for (int r = 0; r < 16; ++r)
            p[r] = __builtin_amdgcn_exp2f(sA[r] + sB[r]);
        {
            float e0 = (p[0] + p[1]) + (p[2] + p[3]);
            float e1 = (p[4] + p[5]) + (p[6] + p[7]);
            float e2 = (p[8] + p[9]) + (p[10] + p[11]);
            float e3 = (p[12] + p[13]) + (p[14] + p[15]);
            den += (e0 + e1) + (e2 + e3);
        }
        // pack P to fp8; one permlane pair builds both PV A-operands
        unsigned u0 = pk4f8(p[0], p[1], p[2], p[3]);
        unsigned u1 = pk4f8(p[4], p[5], p[6], p[7]);
        unsigned u2 = pk4f8(p[8], p[9], p[10], p[11]);
        unsigned u3 = pk4f8(p[12], p[13], p[14], p[15]);
        auto s01 = __builtin_amdgcn_permlane32_swap(u0, u1, false, false);
        auto s23 = __builtin_amdgcn_permlane32_swap(u2, u3, false, false);
        long aP0 = (long)(((unsigned long long)(unsigned)s01[1] << 32) | (unsigned)s01[0]);
        long aP1 = (long)(((unsigned long long)(unsigned)s23[1] << 32) | (unsigned)s23[0]);
        // PV: aP0 with bw8[0..3] (kc=0), aP1 with bw8[4..7] (kc=1)
#pragma unroll
        for (int dt = 0; dt < 4; ++dt) {
            o[dt] = MFMA32F8(aP0, bw8[dt], o[dt]);
            o[dt] = MFMA32F8(aP1, bw8[4 + dt], o[dt]);
        }
        __builtin_amdgcn_sched_barrier(0);
        __builtin_amdgcn_s_barrier();      // all reads of buf done before reuse
        __builtin_amdgcn_sched_barrier(0);
    }

    // ---- cross-sub reduction per q-half (bf16 partials + f32 den) ----
    __syncthreads();
    if (ms >= 1) {
        char* dst = pool + (qh * 3 + (ms - 1)) * 8704 + lane * 136;
#pragma unroll
        for (int t = 0; t < 4; ++t) {
            unsigned u[8];
#pragma unroll
            for (int k = 0; k < 8; ++k) u[k] = pk2(o[t][2 * k], o[t][2 * k + 1]);
            *reinterpret_cast<uint4*>(dst + t * 32) = make_uint4(u[0], u[1], u[2], u[3]);
            *reinterpret_cast<uint4*>(dst + t * 32 + 16) = make_uint4(u[4], u[5], u[6], u[7]);
        }
        *reinterpret_cast<float*>(dst + 128) = den;
    }
    __syncthreads();
    if (ms == 0) {  // waves 0 (qh=0) and 4 (qh=1)
        for (int s = 0; s < 3; ++s) {
            const char* src = pool + (qh * 3 + s) * 8704 + lane * 136;
#pragma unroll
            for (int t = 0; t < 4; ++t) {
                uint4 ua = *reinterpret_cast<const uint4*>(src + t * 32);
                uint4 ub = *reinterpret_cast<const uint4*>(src + t * 32 + 16);
                unsigned u[8] = {ua.x, ua.y, ua.z, ua.w, ub.x, ub.y, ub.z, ub.w};
#pragma unroll
                for (int k = 0; k < 8; ++k) {
                    o[t][2 * k] += bfl(u[k]);
                    o[t][2 * k + 1] += bfh(u[k]);
                }
            }
            den += *reinterpret_cast<const float*>(src + 128);
        }
        den += __shfl_xor(den, 32);
        float invd = 1.0f / den;
        float inv[16];
#pragma unroll
        for (int r = 0; r < 16; ++r)
            inv[r] = __shfl(invd, (r & 3) + 8 * (r >> 2) + 4 * hi);
#pragma unroll
        for (int t = 0; t < 4; ++t)
#pragma unroll
            for (int r = 0; r < 16; ++r) {
                int row = 32 * qh + (r & 3) + 8 * (r >> 2) + 4 * hi;
                float me = o[t][r] * inv[r];
                me_out[(n0 + row) * DD + 32 * t + ml] = me;
                tqm[row * 136 + 32 * t + ml] = f2bf(me);  // me tile for gating
            }
    }
    __syncthreads();

    // ---- fused gating: G = tanh(cat(me,q) @ W_t2^T + b_t2); blend ----
    {
        const int qg = wid >> 2;  // q-half
        const int dt = wid & 3;   // d-tile 32*dt .. 32*dt+31
        f32x16 g = zero16;
#pragma unroll
        for (int c = 0; c < 8; ++c) {  // k < 128: me from LDS tile
            bf16x8 av = ldbf8(&tqm[(32 * qg + ml) * 136 + 16 * c + 8 * hi]);
            bf16x8 bv = ldbf8(wt2f + ((c * 4 + dt) * 64 + lane) * 8);
            g = MFMA32(av, bv, g);
        }
#pragma unroll
        for (int c = 8; c < 16; ++c) {  // k >= 128: query from LDS (f32)
            const float* p = qf32 + (32 * qg + ml) * 132 + 16 * (c - 8) + 8 * hi;
            float4 x0 = *reinterpret_cast<const float4*>(p);
            float4 x1 = *reinterpret_cast<const float4*>(p + 4);
            AW av;
            av.u[0] = pk2(x0.x, x0.y); av.u[1] = pk2(x0.z, x0.w);
            av.u[2] = pk2(x1.x, x1.y); av.u[3] = pk2(x1.z, x1.w);
            bf16x8 bv = ldbf8(wt2f + ((c * 4 + dt) * 64 + lane) * 8);
            g = MFMA32(av.v, bv, g);
        }
        const float TWO_L2E = 2.88539008177792681472f;  // 2*log2(e)
        const int d = 32 * dt + ml;
        const float bias = bt2[d];
#pragma unroll
        for (int r = 0; r < 16; ++r) {
            int row = 32 * qg + (r & 3) + 8 * (r >> 2) + 4 * hi;
            float x = g[r] + bias;
            float gt = 1.0f - 2.0f / (__builtin_amdgcn_exp2f(x * TWO_L2E) + 1.0f);
            float qv = qf32[row * 132 + d];
            float mv = bfl(tqm[row * 136 + d]);
            out[(n0 + row) * DD + d] = qv + gt * (mv - qv);
        }
    }
}

// ---------------------------------------------------------------------------
extern "C" void kernel_launch(void* const* d_in, const int* in_sizes, int n_in,
                              void* d_out, int out_size, void* d_ws, size_t ws_size,
                              hipStream_t stream) {
    const float* query = (const float*)d_in[0];   // [N,128]
    const float* wt    = (const float*)d_in[1];   // [128,128]
    const float* bt    = (const float*)d_in[2];   // [128]
    const float* miw   = (const float*)d_in[3];   // [M,128]
    const float* mw    = (const float*)d_in[4];   // [M,128]
    const float* wt2   = (const float*)d_in[5];   // [128,256]
    const float* bt2   = (const float*)d_in[6];   // [128]

    float* out    = (float*)d_out;                // output 0: [N,128]
    float* me_out = out + (size_t)NQ * DD;        // output 1: mem_emb [N,128]

    // workspace: fp8 m-streams + bf16 weights, ~0.6 MB
    unsigned char* minnA8 = (unsigned char*)d_ws;               // [M/32][8][64][8] fp8
    unsigned char* mwB8   = minnA8 + (size_t)MM * DD;           // [M/32][8][64][8] fp8
    unsigned short* wtb   = (unsigned short*)(mwB8 + (size_t)MM * DD);  // [128][128] bf16
    unsigned short* wt2f  = wtb + (size_t)DD * DD;              // [16][4][64][8] bf16

    k01_prep<<<112, 256, 0, stream>>>(miw, mw, wt, wt2, minnA8, mwB8, wtb, wt2f);
    k3_fused<<<NQ / 64, 512, 0, stream>>>(query, wtb, bt, minnA8, mwB8, wt2f, bt2,
                                          me_out, out);
}

// Round 13
// 39.777 us; speedup vs baseline: 1.2759x; 1.0494x over previous
//
#include <hip/hip_runtime.h>
#include <hip/hip_bf16.h>

#define NQ 16384
#define MM 2048
#define DD 128

typedef __attribute__((ext_vector_type(8))) short bf16x8;
typedef __attribute__((ext_vector_type(4))) float f32x4;
typedef __attribute__((ext_vector_type(16))) float f32x16;

#define MFMA16(a, b, c) __builtin_amdgcn_mfma_f32_16x16x32_bf16((a), (b), (c), 0, 0, 0)
#define MFMA32(a, b, c) __builtin_amdgcn_mfma_f32_32x32x16_bf16((a), (b), (c), 0, 0, 0)
#define MFMA32F8(a, b, c) __builtin_amdgcn_mfma_f32_32x32x16_fp8_fp8((a), (b), (c), 0, 0, 0)

static __device__ __forceinline__ unsigned short f2bf(float x) {
    union { __hip_bfloat16 h; unsigned short u; } cv;
    cv.h = __float2bfloat16(x);
    return cv.u;
}
static __device__ __forceinline__ unsigned pk2(float a, float b) {
    return (unsigned)f2bf(a) | ((unsigned)f2bf(b) << 16);
}
static __device__ __forceinline__ float bfl(unsigned u) {
    union { unsigned v; float f; } c; c.v = u << 16; return c.f;
}
static __device__ __forceinline__ float bfh(unsigned u) {
    union { unsigned v; float f; } c; c.v = u & 0xffff0000u; return c.f;
}
static __device__ __forceinline__ bf16x8 ldbf8(const unsigned short* p) {
    return *reinterpret_cast<const bf16x8*>(p);
}
// pack 4 floats -> 4 fp8 e4m3 bytes (OCP on gfx950)
static __device__ __forceinline__ unsigned pk4f8(float a, float b, float c, float d) {
    int v = __builtin_amdgcn_cvt_pk_fp8_f32(a, b, 0, false);
    v = __builtin_amdgcn_cvt_pk_fp8_f32(c, d, v, true);
    return (unsigned)v;
}
static __device__ __forceinline__ unsigned char f8b(float x) {
    return (unsigned char)(__builtin_amdgcn_cvt_pk_fp8_f32(x, x, 0, false) & 0xff);
}

union AW { unsigned u[4]; bf16x8 v; };

// ---------------------------------------------------------------------------
// K01: prep, fp8 fragment packing for the m-streams (unchanged).
// minnA8[(tile32*8+c)*64+lane][8]; mwB8[(tile32*8+kc*4+dt)*64+lane][8].
// ---------------------------------------------------------------------------
__global__ __launch_bounds__(256) void k01_prep(const float* __restrict__ miw,
                                                const float* __restrict__ mw,
                                                const float* __restrict__ wt,
                                                const float* __restrict__ wt2,
                                                unsigned char* __restrict__ minnA8,
                                                unsigned char* __restrict__ mwB8,
                                                unsigned short* __restrict__ wtb,
                                                unsigned short* __restrict__ wt2f) {
    int b = blockIdx.x;
    int t = threadIdx.x;
    if (b >= 64) {
        int i = (b - 64) * 1024 + t * 4;   // 48 blocks cover 49152 elems
        if (i < DD * DD) {
            float4 x = *reinterpret_cast<const float4*>(wt + i);
            *reinterpret_cast<uint2*>(wtb + i) = make_uint2(pk2(x.x, x.y), pk2(x.z, x.w));
        } else {
            int j = i - DD * DD;           // index into wt2 [128][256]
            float4 x = *reinterpret_cast<const float4*>(wt2 + j);
            int row = j >> 8, col = j & 255;
            unsigned short* dst = wt2f +
                (((((col >> 4) * 4 + (row >> 5)) * 64) + ((col >> 3) & 1) * 32 + (row & 31)) << 3) +
                (col & 7);
            dst[0] = f2bf(x.x); dst[1] = f2bf(x.y); dst[2] = f2bf(x.z); dst[3] = f2bf(x.w);
        }
        return;
    }
    int r = t >> 3;              // tile row 0..31
    int e = t & 7;               // 16-col group 0..7
    int m = b * 32 + r;

    float v[16];
    float ss = 0.f;
#pragma unroll
    for (int k = 0; k < 4; ++k) {
        float4 x = reinterpret_cast<const float4*>(miw + m * DD + e * 16)[k];
        v[4 * k] = x.x; v[4 * k + 1] = x.y; v[4 * k + 2] = x.z; v[4 * k + 3] = x.w;
        ss += x.x * x.x + x.y * x.y + x.z * x.z + x.w * x.w;
    }
    ss += __shfl_xor(ss, 1); ss += __shfl_xor(ss, 2); ss += __shfl_xor(ss, 4);
    float sc = 1.0f / fmaxf(sqrtf(ss), 1e-8f);

    {
        unsigned lo0 = pk4f8(v[0] * sc, v[1] * sc, v[2] * sc, v[3] * sc);
        unsigned lo1 = pk4f8(v[4] * sc, v[5] * sc, v[6] * sc, v[7] * sc);
        unsigned hi0 = pk4f8(v[8] * sc, v[9] * sc, v[10] * sc, v[11] * sc);
        unsigned hi1 = pk4f8(v[12] * sc, v[13] * sc, v[14] * sc, v[15] * sc);
        *reinterpret_cast<uint2*>(minnA8 + ((((b * 8 + e) * 64) + r) << 3)) = make_uint2(lo0, lo1);
        *reinterpret_cast<uint2*>(minnA8 + ((((b * 8 + e) * 64) + 32 + r) << 3)) = make_uint2(hi0, hi1);
    }

    float w[16];
#pragma unroll
    for (int k = 0; k < 4; ++k) {
        float4 x = reinterpret_cast<const float4*>(mw + m * DD + e * 16)[k];
        w[4 * k] = x.x; w[4 * k + 1] = x.y; w[4 * k + 2] = x.z; w[4 * k + 3] = x.w;
    }
    int kc = r >> 4, hh = (r >> 3) & 1, jj = r & 7;
    unsigned char* base = mwB8 +
        ((((b * 8 + kc * 4 + (e >> 1)) * 64) + hh * 32 + (e & 1) * 16) << 3) + jj;
#pragma unroll
    for (int u = 0; u < 16; ++u) base[u << 3] = f8b(w[u]);
}

// ---------------------------------------------------------------------------
// K3: fused transform + attention + gating.  LDS staging, triple-buffered:
// Grid 256 x 512thr (1 block/CU; 8 waves = 2 q-halves x 4 m-subs).
// Per iter: {s_barrier; stage(it+2) DMA; vmcnt(8); compute buf[it%3]} —
// ONE barrier/iter, 2 tiles (64 KB) in DMA flight.  Per-block tile ROTATION
// (rot = bid&15) decorrelates the 256 blocks' identical address streams to
// kill same-L2-line contention.  Epilogue unchanged (reduction + gating).
// ---------------------------------------------------------------------------
__global__ __launch_bounds__(512, 1) void k3_fused(const float* __restrict__ query,
                                                   const unsigned short* __restrict__ wtb,
                                                   const float* __restrict__ bt,
                                                   const unsigned char* __restrict__ minnA8,
                                                   const unsigned char* __restrict__ mwB8,
                                                   const unsigned short* __restrict__ wt2f,
                                                   const float* __restrict__ bt2,
                                                   float* __restrict__ me_out,
                                                   float* __restrict__ out) {
    // [0,98304):        3 staging buffers of 32 KB (each: 16K minn + 16K mw)
    //                   (aliased post-loop: 6 reduction slots of 8704 B)
    // [98304,115712):   tqm 64 rows x 136 shorts (tq_n bf16; later me tile)
    // [115712,149504):  qf32 raw query tile, 64 rows x 132 floats
    __shared__ __align__(16) char pool[149504];
    unsigned short* tqm = reinterpret_cast<unsigned short*>(pool + 98304);
    float* qf32 = reinterpret_cast<float*>(pool + 115712);

    const int lane = threadIdx.x & 63;
    const int wid = threadIdx.x >> 6;   // 0..7
    const int qh = wid >> 2;            // q-half (32 q)
    const int ms = wid & 3;             // m-sub (32 m of each 128-m tile)
    const int ml = lane & 31;
    const int hi = lane >> 5;
    const int n0 = blockIdx.x * 64;
    const int rot = blockIdx.x & 15;
    const float L2E = 1.44269504088896340736f;

    // stage one 128-m tile (32 KB: minn 16K + mw 16K) into buf; wave w does
    // 4 x 1KB segments.  Images are exact copies -> fragment offsets preserved.
    auto stage = [&](int ti, char* buf) {
        const unsigned char* garr = (wid < 4) ? minnA8 : mwB8;
        const int reg = (wid & 3) * 4096;
        const int ldsb = ((wid < 4) ? 0 : 16384) + reg;
#pragma unroll
        for (int k = 0; k < 4; ++k) {
            const unsigned char* src = garr + (size_t)ti * 16384 + reg + k * 1024 + lane * 16;
            __builtin_amdgcn_global_load_lds(
                (const __attribute__((address_space(1))) unsigned int*)src,
                (__attribute__((address_space(3))) unsigned int*)(buf + ldsb + k * 1024),
                16, 0, 0);
        }
    };

    // prologue: start DMA of tiles 0,1 (land under phase-0 compute)
    stage(rot, pool);
    stage((rot + 1) & 15, pool + 32768);

    // ---- Phase 0: transform 64 q (waves 0..3, 16 q each); stash raw q f32
    if (wid < 4) {
        const int nl = lane & 15;
        const int g = lane >> 4;
        const int qb = n0 + 16 * wid;
        AW aq[4];
#pragma unroll
        for (int c = 0; c < 4; ++c) {
            const float* p = query + (qb + nl) * DD + 32 * c + 8 * g;
            float4 x0 = reinterpret_cast<const float4*>(p)[0];
            float4 x1 = reinterpret_cast<const float4*>(p)[1];
            aq[c].u[0] = pk2(x0.x, x0.y); aq[c].u[1] = pk2(x0.z, x0.w);
            aq[c].u[2] = pk2(x1.x, x1.y); aq[c].u[3] = pk2(x1.z, x1.w);
            float* qd = qf32 + (16 * wid + nl) * 132 + 32 * c + 8 * g;
            *reinterpret_cast<float4*>(qd) = x0;
            *reinterpret_cast<float4*>(qd + 4) = x1;
        }
        f32x4 acc[8];
#pragma unroll
        for (int t = 0; t < 8; ++t) acc[t] = (f32x4){0.f, 0.f, 0.f, 0.f};
#pragma unroll
        for (int t = 0; t < 8; ++t)
#pragma unroll
            for (int c = 0; c < 4; ++c) {
                bf16x8 bv = ldbf8(wtb + (16 * t + nl) * DD + 32 * c + 8 * g);
                acc[t] = MFMA16(aq[c].v, bv, acc[t]);
            }
        float ss[4] = {0.f, 0.f, 0.f, 0.f};
#pragma unroll
        for (int t = 0; t < 8; ++t) {
            float bias = bt[16 * t + nl];
#pragma unroll
            for (int r = 0; r < 4; ++r) {
                float vv = acc[t][r] + bias;
                acc[t][r] = vv;
                ss[r] += vv * vv;
            }
        }
#pragma unroll
        for (int r = 0; r < 4; ++r) {
            ss[r] += __shfl_xor(ss[r], 1);
            ss[r] += __shfl_xor(ss[r], 2);
            ss[r] += __shfl_xor(ss[r], 4);
            ss[r] += __shfl_xor(ss[r], 8);
        }
        float scl[4];
#pragma unroll
        for (int r = 0; r < 4; ++r) scl[r] = L2E / fmaxf(sqrtf(ss[r]), 1e-8f);
#pragma unroll
        for (int t = 0; t < 8; ++t)
#pragma unroll
            for (int r = 0; r < 4; ++r)
                tqm[(16 * wid + 4 * g + r) * 136 + 16 * t + nl] = f2bf(acc[t][r] * scl[r]);
    }
    __syncthreads();  // tqm/qf32 visible; tiles 0,1 DMA drained (implicit vmcnt0)

    // Qn fp8 B-fragments for this wave's q-half, built from the bf16 tile
    long qn8[8];
#pragma unroll
    for (int c = 0; c < 8; ++c) {
        bf16x8 qv = ldbf8(&tqm[(32 * qh + ml) * 136 + 16 * c + 8 * hi]);
        const unsigned* qu = reinterpret_cast<const unsigned*>(&qv);
        unsigned lo = pk4f8(bfl(qu[0]), bfh(qu[0]), bfl(qu[1]), bfh(qu[1]));
        unsigned hh = pk4f8(bfl(qu[2]), bfh(qu[2]), bfl(qu[3]), bfh(qu[3]));
        qn8[c] = (long)(((unsigned long long)hh << 32) | lo);
    }

    const f32x16 zero16 = {0.f,0.f,0.f,0.f,0.f,0.f,0.f,0.f,0.f,0.f,0.f,0.f,0.f,0.f,0.f,0.f};
    f32x16 o[4];
#pragma unroll
    for (int t = 0; t < 4; ++t) o[t] = zero16;
    float den = 0.0f;

    for (int it = 0; it < 16; ++it) {
        // barrier FIRST: all waves done computing it-1 -> safe to overwrite
        // buf[(it+2)%3] (== buf[(it-1)%3]) with the it+2 stage.
        __builtin_amdgcn_s_barrier();
        if (it < 14) {
            stage((it + 2 + rot) & 15, pool + ((it + 2) % 3) * 32768);
            asm volatile("s_waitcnt vmcnt(8)" ::: "memory");   // tile `it` landed
        } else if (it == 14) {
            asm volatile("s_waitcnt vmcnt(4)" ::: "memory");
        } else {
            asm volatile("s_waitcnt vmcnt(0)" ::: "memory");
        }
        __builtin_amdgcn_sched_barrier(0);

        const char* buf = pool + (it % 3) * 32768;
        const char* amin = buf + ms * 4096 + lane * 8;
        const char* bmw = buf + 16384 + ms * 4096 + lane * 8;
        long aA8[8], bw8[8];
#pragma unroll
        for (int c = 0; c < 8; ++c) {
            aA8[c] = *reinterpret_cast<const long*>(amin + c * 512);
            bw8[c] = *reinterpret_cast<const long*>(bmw + c * 512);
        }

        // QK^T: D[m][n], two 4-deep accumulate chains over d (K=16 each)
        f32x16 sA = zero16, sB = zero16;
#pragma unroll
        for (int c = 0; c < 4; ++c) sA = MFMA32F8(aA8[c], qn8[c], sA);
#pragma unroll
        for (int c = 4; c < 8; ++c) sB = MFMA32F8(aA8[c], qn8[c], sB);

        float p[16];
#pragma unroll
        for (int r = 0; r < 16; ++r)
            p[r] = __builtin_amdgcn_exp2f(sA[r] + sB[r]);
        {
            float e0 = (p[0] + p[1]) + (p[2] + p[3]);
            float e1 = (p[4] + p[5]) + (p[6] + p[7]);
            float e2 = (p[8] + p[9]) + (p[10] + p[11]);
            float e3 = (p[12] + p[13]) + (p[14] + p[15]);
            den += (e0 + e1) + (e2 + e3);
        }
        // pack P to fp8; one permlane pair builds both PV A-operands
        unsigned u0 = pk4f8(p[0], p[1], p[2], p[3]);
        unsigned u1 = pk4f8(p[4], p[5], p[6], p[7]);
        unsigned u2 = pk4f8(p[8], p[9], p[10], p[11]);
        unsigned u3 = pk4f8(p[12], p[13], p[14], p[15]);
        auto s01 = __builtin_amdgcn_permlane32_swap(u0, u1, false, false);
        auto s23 = __builtin_amdgcn_permlane32_swap(u2, u3, false, false);
        long aP0 = (long)(((unsigned long long)(unsigned)s01[1] << 32) | (unsigned)s01[0]);
        long aP1 = (long)(((unsigned long long)(unsigned)s23[1] << 32) | (unsigned)s23[0]);
        // PV: aP0 with bw8[0..3] (kc=0), aP1 with bw8[4..7] (kc=1)
#pragma unroll
        for (int dt = 0; dt < 4; ++dt) {
            o[dt] = MFMA32F8(aP0, bw8[dt], o[dt]);
            o[dt] = MFMA32F8(aP1, bw8[4 + dt], o[dt]);
        }
    }

    // ---- cross-sub reduction per q-half (bf16 partials + f32 den) ----
    __syncthreads();
    if (ms >= 1) {
        char* dst = pool + (qh * 3 + (ms - 1)) * 8704 + lane * 136;
#pragma unroll
        for (int t = 0; t < 4; ++t) {
            unsigned u[8];
#pragma unroll
            for (int k = 0; k < 8; ++k) u[k] = pk2(o[t][2 * k], o[t][2 * k + 1]);
            *reinterpret_cast<uint4*>(dst + t * 32) = make_uint4(u[0], u[1], u[2], u[3]);
            *reinterpret_cast<uint4*>(dst + t * 32 + 16) = make_uint4(u[4], u[5], u[6], u[7]);
        }
        *reinterpret_cast<float*>(dst + 128) = den;
    }
    __syncthreads();
    if (ms == 0) {  // waves 0 (qh=0) and 4 (qh=1)
        for (int s = 0; s < 3; ++s) {
            const char* src = pool + (qh * 3 + s) * 8704 + lane * 136;
#pragma unroll
            for (int t = 0; t < 4; ++t) {
                uint4 ua = *reinterpret_cast<const uint4*>(src + t * 32);
                uint4 ub = *reinterpret_cast<const uint4*>(src + t * 32 + 16);
                unsigned u[8] = {ua.x, ua.y, ua.z, ua.w, ub.x, ub.y, ub.z, ub.w};
#pragma unroll
                for (int k = 0; k < 8; ++k) {
                    o[t][2 * k] += bfl(u[k]);
                    o[t][2 * k + 1] += bfh(u[k]);
                }
            }
            den += *reinterpret_cast<const float*>(src + 128);
        }
        den += __shfl_xor(den, 32);
        float invd = 1.0f / den;
        float inv[16];
#pragma unroll
        for (int r = 0; r < 16; ++r)
            inv[r] = __shfl(invd, (r & 3) + 8 * (r >> 2) + 4 * hi);
#pragma unroll
        for (int t = 0; t < 4; ++t)
#pragma unroll
            for (int r = 0; r < 16; ++r) {
                int row = 32 * qh + (r & 3) + 8 * (r >> 2) + 4 * hi;
                float me = o[t][r] * inv[r];
                me_out[(n0 + row) * DD + 32 * t + ml] = me;
                tqm[row * 136 + 32 * t + ml] = f2bf(me);  // me tile for gating
            }
    }
    __syncthreads();

    // ---- fused gating: G = tanh(cat(me,q) @ W_t2^T + b_t2); blend ----
    {
        const int qg = wid >> 2;  // q-half
        const int dt = wid & 3;   // d-tile 32*dt .. 32*dt+31
        f32x16 g = zero16;
#pragma unroll
        for (int c = 0; c < 8; ++c) {  // k < 128: me from LDS tile
            bf16x8 av = ldbf8(&tqm[(32 * qg + ml) * 136 + 16 * c + 8 * hi]);
            bf16x8 bv = ldbf8(wt2f + ((c * 4 + dt) * 64 + lane) * 8);
            g = MFMA32(av, bv, g);
        }
#pragma unroll
        for (int c = 8; c < 16; ++c) {  // k >= 128: query from LDS (f32)
            const float* p = qf32 + (32 * qg + ml) * 132 + 16 * (c - 8) + 8 * hi;
            float4 x0 = *reinterpret_cast<const float4*>(p);
            float4 x1 = *reinterpret_cast<const float4*>(p + 4);
            AW av;
            av.u[0] = pk2(x0.x, x0.y); av.u[1] = pk2(x0.z, x0.w);
            av.u[2] = pk2(x1.x, x1.y); av.u[3] = pk2(x1.z, x1.w);
            bf16x8 bv = ldbf8(wt2f + ((c * 4 + dt) * 64 + lane) * 8);
            g = MFMA32(av.v, bv, g);
        }
        const float TWO_L2E = 2.88539008177792681472f;  // 2*log2(e)
        const int d = 32 * dt + ml;
        const float bias = bt2[d];
#pragma unroll
        for (int r = 0; r < 16; ++r) {
            int row = 32 * qg + (r & 3) + 8 * (r >> 2) + 4 * hi;
            float x = g[r] + bias;
            float gt = 1.0f - 2.0f / (__builtin_amdgcn_exp2f(x * TWO_L2E) + 1.0f);
            float qv = qf32[row * 132 + d];
            float mv = bfl(tqm[row * 136 + d]);
            out[(n0 + row) * DD + d] = qv + gt * (mv - qv);
        }
    }
}

// ---------------------------------------------------------------------------
extern "C" void kernel_launch(void* const* d_in, const int* in_sizes, int n_in,
                              void* d_out, int out_size, void* d_ws, size_t ws_size,
                              hipStream_t stream) {
    const float* query = (const float*)d_in[0];   // [N,128]
    const float* wt    = (const float*)d_in[1];   // [128,128]
    const float* bt    = (const float*)d_in[2];   // [128]
    const float* miw   = (const float*)d_in[3];   // [M,128]
    const float* mw    = (const float*)d_in[4];   // [M,128]
    const float* wt2   = (const float*)d_in[5];   // [128,256]
    const float* bt2   = (const float*)d_in[6];   // [128]

    float* out    = (float*)d_out;                // output 0: [N,128]
    float* me_out = out + (size_t)NQ * DD;        // output 1: mem_emb [N,128]

    // workspace: fp8 m-streams + bf16 weights, ~0.6 MB
    unsigned char* minnA8 = (unsigned char*)d_ws;               // [M/32][8][64][8] fp8
    unsigned char* mwB8   = minnA8 + (size_t)MM * DD;           // [M/32][8][64][8] fp8
    unsigned short* wtb   = (unsigned short*)(mwB8 + (size_t)MM * DD);  // [128][128] bf16
    unsigned short* wt2f  = wtb + (size_t)DD * DD;              // [16][4][64][8] bf16

    k01_prep<<<112, 256, 0, stream>>>(miw, mw, wt, wt2, minnA8, mwB8, wtb, wt2f);
    k3_fused<<<NQ / 64, 512, 0, stream>>>(query, wtb, bt, minnA8, mwB8, wt2f, bt2,
                                          me_out, out);
}